// Round 12
// baseline (262.441 us; speedup 1.0000x reference)
//
#include <hip/hip_runtime.h>
#include <hip/hip_bf16.h>

#define IN_F  128
#define HID_F 256
#define OUT_F 64
#define BUCKET_SHIFT 9
#define BUCKET_SZ 512
#define EPB 4096            // edges per binning block (1024 threads, 4 iters)
#define CAP 10240           // fixed bucket capacity (mean 8190, +22 sigma)

typedef __attribute__((ext_vector_type(8))) short bf16x8;
typedef __attribute__((ext_vector_type(4))) float f32x4;

__device__ __forceinline__ float bf2f(unsigned short u) {
    union { unsigned int i; float f; } v; v.i = ((unsigned int)u) << 16; return v.f;
}
__device__ __forceinline__ float bf2f_lo(unsigned int p) {
    union { unsigned int i; float f; } v; v.i = p << 16; return v.f;
}
__device__ __forceinline__ float bf2f_hi(unsigned int p) {
    union { unsigned int i; float f; } v; v.i = p & 0xffff0000u; return v.f;
}
__device__ __forceinline__ unsigned short f2bf(float f) {
    __hip_bfloat16 b = __float2bfloat16(f);
    return *reinterpret_cast<unsigned short*>(&b);
}

// ---- Fused front: xconv | W12=W1@W2 | bin (all independent, one launch) -
// Linear net (eps=0, no bias/act): z = (x+agg) @ (W1@W2). W12 is 128x64.
// bin: LDS hist -> one global atomicAdd per (block,bucket) reserves a
// contiguous run in bucket region b*CAP -> scatter packed records.
// pack = (dlocal<<23) | src  (dlocal 9 bits, src < 2^17).
__global__ __launch_bounds__(1024) void k_front_bin(
    const float* __restrict__ x, unsigned short* __restrict__ xb, long long total8,
    const float* __restrict__ W1, const float* __restrict__ W2,
    unsigned short* __restrict__ w12s,
    const int* __restrict__ esrc, const int* __restrict__ edst,
    int* __restrict__ gcur, unsigned int* __restrict__ binned,
    int nEdges, int xBlocks)
{
    __shared__ int hist[256];   // NB <= 256
    __shared__ int lcur[256];
    int bid = blockIdx.x;
    int t = threadIdx.x;
    if (bid < xBlocks) {
        long long i = (long long)bid * 1024 + t;
        if (i >= total8) return;
        const float4* p = reinterpret_cast<const float4*>(x) + i * 2;
        float4 a = p[0], b = p[1];
        ushort4 o0, o1;
        o0.x = f2bf(a.x); o0.y = f2bf(a.y); o0.z = f2bf(a.z); o0.w = f2bf(a.w);
        o1.x = f2bf(b.x); o1.y = f2bf(b.y); o1.z = f2bf(b.z); o1.w = f2bf(b.w);
        reinterpret_cast<ushort4*>(xb)[i * 2]     = o0;
        reinterpret_cast<ushort4*>(xb)[i * 2 + 1] = o1;
    } else if (bid < xBlocks + 8) {
        // W12 in B-frag order: chunk c=nt*4+ks; lane L; elem j:
        // k=ks*32+(L>>4)*8+j, n=nt*16+(L&15)
        int idx = (bid - xBlocks) * 1024 + t;    // 0..8191
        int c = idx >> 9, L = (idx >> 3) & 63, j = idx & 7;
        int nt = c >> 2, ks = c & 3;
        int k = ks * 32 + (L >> 4) * 8 + j;
        int n = nt * 16 + (L & 15);
        float s = 0.f;
        #pragma unroll 8
        for (int jj = 0; jj < HID_F; ++jj)
            s += W1[k * HID_F + jj] * W2[jj * OUT_F + n];
        w12s[idx] = f2bf(s);
    } else {
        int bb = bid - xBlocks - 8;              // binning block 0..A-1
        if (t < 256) hist[t] = 0;
        __syncthreads();
        long long base = (long long)bb * EPB;
        #pragma unroll
        for (int k = 0; k < EPB / 1024; ++k) {
            long long e = base + k * 1024 + t;
            if (e < nEdges) atomicAdd(&hist[edst[e] >> BUCKET_SHIFT], 1);
        }
        __syncthreads();
        if (t < 256) {
            int h = hist[t];
            lcur[t] = (h > 0) ? atomicAdd(&gcur[t], h) : 0;
        }
        __syncthreads();
        #pragma unroll
        for (int k = 0; k < EPB / 1024; ++k) {
            long long e = base + k * 1024 + t;
            if (e < nEdges) {
                int s = esrc[e], d = edst[e];
                int b = d >> BUCKET_SHIFT;
                int pos = atomicAdd(&lcur[b], 1);
                binned[(size_t)b * CAP + pos] =
                    (((unsigned int)(d & (BUCKET_SZ - 1))) << 23) | (unsigned int)s;
            }
        }
    }
}

// ---- Per-bucket local CSR (512 threads, 1 thread/node) ------------------
__global__ __launch_bounds__(512) void k_localcsr(
    const unsigned int* __restrict__ binned, const int* __restrict__ gcur,
    int* __restrict__ rowbeg, int* __restrict__ rowend,
    int* __restrict__ eidx, int nNodes)
{
    __shared__ int ldeg[BUCKET_SZ];
    __shared__ int lscan[BUCKET_SZ];
    int t = threadIdx.x;          // 0..511
    ldeg[t] = 0;
    __syncthreads();
    int eb0 = blockIdx.x * CAP;
    int cnt = gcur[blockIdx.x];
    int node0 = blockIdx.x << BUCKET_SHIFT;
    for (int e = t; e < cnt; e += 512)
        atomicAdd(&ldeg[binned[eb0 + e] >> 23], 1);
    __syncthreads();
    int s = ldeg[t];
    lscan[t] = s;
    __syncthreads();
    for (int d = 1; d < 512; d <<= 1) {
        int add = (t >= d) ? lscan[t - d] : 0;
        __syncthreads();
        lscan[t] += add;
        __syncthreads();
    }
    int excl = lscan[t] - s;
    int n0 = node0 + t;
    if (n0 < nNodes) { rowbeg[n0] = eb0 + excl; rowend[n0] = eb0 + excl + s; }
    __syncthreads();
    ldeg[t] = excl;               // becomes local cursor
    __syncthreads();
    for (int e = t; e < cnt; e += 512) {
        unsigned int p = binned[eb0 + e];
        int dl = (int)(p >> 23), sv = (int)(p & 0x7fffffu);
        int pos = atomicAdd(&ldeg[dl], 1);
        eidx[eb0 + pos] = sv;
    }
}

// ---- Fused gather1 + z GEMM: z = (xb[n]+sum xb[src]) @ W12 --------------
// 64 nodes/block, 16 waves; each wave gathers 4 nodes SEQUENTIALLY
// (degree-averaging halves barrier imbalance vs 1 node/wave). Rows land in
// 4 XOR-swizzled 4KB LDS tiles; one barrier; all 16 waves run the GEMM
// (wave -> tile=w>>2, nt=w&3). No global agg round-trip.
__global__ __launch_bounds__(1024) void gather1z(
    const unsigned short* __restrict__ xb, const int* __restrict__ rowbeg,
    const int* __restrict__ rowend, const int* __restrict__ eidx,
    const unsigned short* __restrict__ w12s,
    unsigned short* __restrict__ z, int nNodes)
{
    __shared__ unsigned short aggT[64 * IN_F];   // 16KB = 4 tiles x 4KB
    int wave = threadIdx.x >> 6, lane = threadIdx.x & 63;
    int m0 = blockIdx.x * 64;
    int g = lane >> 4;          // edge subgroup 0..3
    int f = lane & 15;          // 16B chunk within row
    char* scb = reinterpret_cast<char*>(aggT);

    for (int j = 0; j < 4; ++j) {
        int r = wave * 4 + j;                    // local row 0..63
        int n = m0 + r;
        char* sc = scb + ((r >> 4) << 12);       // tile base
        int lr = r & 15;
        int wb = ((lr << 8) + (f << 4)) ^ ((lr & 7) << 4);
        if (n < nNodes) {
            int beg = __builtin_amdgcn_readfirstlane(rowbeg[n]);
            int end = __builtin_amdgcn_readfirstlane(rowend[n]);
            float acc[8] = {0.f, 0.f, 0.f, 0.f, 0.f, 0.f, 0.f, 0.f};
            for (int e0 = beg; e0 < end; e0 += 64) {
                int cnt = min(64, end - e0);             // uniform
                int e = (lane < cnt) ? eidx[e0 + lane] : 0;
                for (int i = 0; i < cnt; i += 16) {      // 16 edges per block
                    uint4 v[4];
                    unsigned int vmask[4];
                    #pragma unroll
                    for (int jj = 0; jj < 4; ++jj) {
                        int eij = i + 4 * jj + g;
                        int src = __builtin_amdgcn_ds_bpermute(eij << 2, e);
                        int s0  = __builtin_amdgcn_readlane(e, i + 4 * jj);
                        bool valid = eij < cnt;
                        vmask[jj] = valid ? 0xffffffffu : 0u;
                        src = valid ? src : s0;          // same lines, no extra fetch
                        v[jj] = *reinterpret_cast<const uint4*>(
                            xb + (unsigned)src * IN_F + (f << 3));
                    }
                    #pragma unroll
                    for (int jj = 0; jj < 4; ++jj) {
                        unsigned int a0 = v[jj].x & vmask[jj], a1 = v[jj].y & vmask[jj];
                        unsigned int a2 = v[jj].z & vmask[jj], a3 = v[jj].w & vmask[jj];
                        acc[0] += bf2f_lo(a0); acc[1] += bf2f_hi(a0);
                        acc[2] += bf2f_lo(a1); acc[3] += bf2f_hi(a1);
                        acc[4] += bf2f_lo(a2); acc[5] += bf2f_hi(a2);
                        acc[6] += bf2f_lo(a3); acc[7] += bf2f_hi(a3);
                    }
                }
            }
            #pragma unroll
            for (int k = 0; k < 8; ++k) {
                acc[k] += __shfl_xor(acc[k], 16);
                acc[k] += __shfl_xor(acc[k], 32);
            }
            uint4 sv = *reinterpret_cast<const uint4*>(xb + (size_t)n * IN_F + (f << 3));
            acc[0] += bf2f_lo(sv.x); acc[1] += bf2f_hi(sv.x);
            acc[2] += bf2f_lo(sv.y); acc[3] += bf2f_hi(sv.y);
            acc[4] += bf2f_lo(sv.z); acc[5] += bf2f_hi(sv.z);
            acc[6] += bf2f_lo(sv.w); acc[7] += bf2f_hi(sv.w);
            if (g == 0) {
                uint4 o;
                o.x = (unsigned int)f2bf(acc[0]) | ((unsigned int)f2bf(acc[1]) << 16);
                o.y = (unsigned int)f2bf(acc[2]) | ((unsigned int)f2bf(acc[3]) << 16);
                o.z = (unsigned int)f2bf(acc[4]) | ((unsigned int)f2bf(acc[5]) << 16);
                o.w = (unsigned int)f2bf(acc[6]) | ((unsigned int)f2bf(acc[7]) << 16);
                *reinterpret_cast<uint4*>(sc + wb) = o;
            }
        } else {
            if (g == 0) *reinterpret_cast<uint4*>(sc + wb) = make_uint4(0, 0, 0, 0);
        }
    }
    __syncthreads();

    // ---- GEMM phase: all 16 waves; wave -> tile = w>>2, nt = w&3 --------
    {
        int tile = wave >> 2, nt = wave & 3;
        char* sc = scb + (tile << 12);
        int row = lane & 15, quad = lane >> 4;
        f32x4 acc2 = {};
        const bf16x8* bBase = reinterpret_cast<const bf16x8*>(w12s) + lane;
        #pragma unroll
        for (int ks = 0; ks < 4; ++ks) {
            int ab = ((row << 8) + (quad << 4) + (ks << 6)) ^ ((row & 7) << 4);
            bf16x8 a = *reinterpret_cast<const bf16x8*>(sc + ab);
            bf16x8 b = bBase[(nt * 4 + ks) * 64];
            acc2 = __builtin_amdgcn_mfma_f32_16x16x32_bf16(a, b, acc2, 0, 0, 0);
        }
        int mt = m0 + tile * 16;
        size_t outBase = (size_t)(mt + quad * 4) * OUT_F + nt * 16 + row;
        #pragma unroll
        for (int i = 0; i < 4; ++i) {
            if (mt + quad * 4 + i >= nNodes) break;   // tail guard
            z[outBase + (size_t)i * OUT_F] = f2bf(acc2[i]);
        }
    }
}

// ---- Layer-2 gather (commuted): out[n] = z[n] + sum z[src] --------------
// Wide-gather: 8 lanes cover a 128B z-row (dwordx4/lane) -> 8 edges/instr.
__global__ __launch_bounds__(256) void gather2(
    const unsigned short* __restrict__ z, const int* __restrict__ rowbeg,
    const int* __restrict__ rowend,
    const int* __restrict__ eidx, float* __restrict__ out, int nNodes)
{
    int n    = blockIdx.x * 4 + __builtin_amdgcn_readfirstlane(threadIdx.x >> 6);
    int lane = threadIdx.x & 63;
    if (n >= nNodes) return;
    int beg = __builtin_amdgcn_readfirstlane(rowbeg[n]);
    int end = __builtin_amdgcn_readfirstlane(rowend[n]);
    int g = lane >> 3;          // edge subgroup 0..7
    int f = lane & 7;           // 16B chunk within row
    float acc[8] = {0.f, 0.f, 0.f, 0.f, 0.f, 0.f, 0.f, 0.f};

    for (int e0 = beg; e0 < end; e0 += 64) {
        int cnt = min(64, end - e0);                 // uniform
        int e = (lane < cnt) ? eidx[e0 + lane] : 0;
        for (int i = 0; i < cnt; i += 32) {          // 32 edges per block
            uint4 v[4];
            unsigned int vmask[4];
            #pragma unroll
            for (int j = 0; j < 4; ++j) {
                int eij = i + 8 * j + g;
                int src = __builtin_amdgcn_ds_bpermute(eij << 2, e);
                int s0  = __builtin_amdgcn_readlane(e, i + 8 * j);
                bool valid = eij < cnt;
                vmask[j] = valid ? 0xffffffffu : 0u;
                src = valid ? src : s0;
                v[j] = *reinterpret_cast<const uint4*>(
                    z + (unsigned)src * OUT_F + (f << 3));
            }
            #pragma unroll
            for (int j = 0; j < 4; ++j) {
                unsigned int a0 = v[j].x & vmask[j], a1 = v[j].y & vmask[j];
                unsigned int a2 = v[j].z & vmask[j], a3 = v[j].w & vmask[j];
                acc[0] += bf2f_lo(a0); acc[1] += bf2f_hi(a0);
                acc[2] += bf2f_lo(a1); acc[3] += bf2f_hi(a1);
                acc[4] += bf2f_lo(a2); acc[5] += bf2f_hi(a2);
                acc[6] += bf2f_lo(a3); acc[7] += bf2f_hi(a3);
            }
        }
    }
    // cross-subgroup reduce (8 groups share feature chunks)
    #pragma unroll
    for (int k = 0; k < 8; ++k) {
        acc[k] += __shfl_xor(acc[k], 8);
        acc[k] += __shfl_xor(acc[k], 16);
        acc[k] += __shfl_xor(acc[k], 32);
    }
    // self row add
    uint4 sv = *reinterpret_cast<const uint4*>(z + (size_t)n * OUT_F + (f << 3));
    acc[0] += bf2f_lo(sv.x); acc[1] += bf2f_hi(sv.x);
    acc[2] += bf2f_lo(sv.y); acc[3] += bf2f_hi(sv.y);
    acc[4] += bf2f_lo(sv.z); acc[5] += bf2f_hi(sv.z);
    acc[6] += bf2f_lo(sv.w); acc[7] += bf2f_hi(sv.w);
    if (g == 0) {
        float* o = out + (size_t)n * OUT_F + (f << 3);
        *reinterpret_cast<float4*>(o)     = make_float4(acc[0], acc[1], acc[2], acc[3]);
        *reinterpret_cast<float4*>(o + 4) = make_float4(acc[4], acc[5], acc[6], acc[7]);
    }
}

extern "C" void kernel_launch(void* const* d_in, const int* in_sizes, int n_in,
                              void* d_out, int out_size, void* d_ws, size_t ws_size,
                              hipStream_t stream) {
    const float* x  = (const float*)d_in[0];
    const int* esrc = (const int*)d_in[1];
    const int* edst = (const int*)d_in[2];
    const float* W1 = (const float*)d_in[3];
    const float* W2 = (const float*)d_in[4];
    float* out      = (float*)d_out;

    const int nNodes = in_sizes[0] / IN_F;
    const int nEdges = in_sizes[1];
    const int NB = (nNodes + BUCKET_SZ - 1) / BUCKET_SZ;   // 196 (<= 256)
    const int A  = (nEdges + EPB - 1) / EPB;               // 391 binning blocks

    // Workspace (~56 MB; 110.4 MB known-safe), 64B-aligned segments.
    char* ws = (char*)d_ws;
    size_t off = 0;
    auto alloc = [&](size_t bytes) {
        char* p = ws + off; off = (off + bytes + 63) & ~(size_t)63; return p;
    };
    unsigned short* xb  = (unsigned short*)alloc((size_t)nNodes * IN_F * 2);
    unsigned short* z   = (unsigned short*)alloc((size_t)nNodes * OUT_F * 2);
    unsigned int* binned = (unsigned int*)alloc((size_t)NB * CAP * 4);
    int* eidx           = (int*)alloc((size_t)NB * CAP * 4);
    unsigned short* w12s = (unsigned short*)alloc((size_t)IN_F * OUT_F * 2);
    int* rowbeg         = (int*)alloc((size_t)nNodes * 4);
    int* rowend         = (int*)alloc((size_t)nNodes * 4);
    int* gcur           = (int*)alloc(256 * 4);

    hipMemsetAsync(gcur, 0, 256 * 4, stream);

    // ---- fused front: xconv | W12 | bin ----
    long long total8 = (long long)nNodes * IN_F / 8;
    const int xBlocks = (int)((total8 + 1023) / 1024);     // 1563
    k_front_bin<<<xBlocks + 8 + A, 1024, 0, stream>>>(
        x, xb, total8, W1, W2, w12s, esrc, edst, gcur, binned, nEdges, xBlocks);

    k_localcsr<<<NB, 512, 0, stream>>>(binned, gcur, rowbeg, rowend, eidx, nNodes);

    const int g1Blocks = (nNodes + 63) / 64;
    const int nBlocks = (nNodes + 3) / 4;
    gather1z<<<g1Blocks, 1024, 0, stream>>>(xb, rowbeg, rowend, eidx, w12s, z, nNodes);
    gather2<<<nBlocks, 256, 0, stream>>>(z, rowbeg, rowend, eidx, out, nNodes);
}

// Round 13
// 244.337 us; speedup vs baseline: 1.0741x; 1.0741x over previous
//
#include <hip/hip_runtime.h>
#include <hip/hip_bf16.h>

#define IN_F  128
#define HID_F 256
#define OUT_F 64
#define BUCKET_SHIFT 9
#define BUCKET_SZ 512
#define EPB 4096            // edges per binning block (1024 threads, 4 iters)
#define CAP 10240           // fixed bucket capacity (mean 8190, +22 sigma)

typedef __attribute__((ext_vector_type(8))) short bf16x8;
typedef __attribute__((ext_vector_type(4))) float f32x4;

__device__ __forceinline__ float bf2f(unsigned short u) {
    union { unsigned int i; float f; } v; v.i = ((unsigned int)u) << 16; return v.f;
}
__device__ __forceinline__ float bf2f_lo(unsigned int p) {
    union { unsigned int i; float f; } v; v.i = p << 16; return v.f;
}
__device__ __forceinline__ float bf2f_hi(unsigned int p) {
    union { unsigned int i; float f; } v; v.i = p & 0xffff0000u; return v.f;
}
__device__ __forceinline__ unsigned short f2bf(float f) {
    __hip_bfloat16 b = __float2bfloat16(f);
    return *reinterpret_cast<unsigned short*>(&b);
}

// ---- Fused front: W12=W1@W2 (swizzled) | bin -----------------------------
// Full linearity: out = (I+A)^2 (x @ W12). W12 computed once (128x64);
// bin: LDS hist -> one global atomicAdd per (block,bucket) reserves a
// contiguous run in bucket region b*CAP -> scatter packed records.
// pack = (dlocal<<23) | src  (dlocal 9 bits, src < 2^17).
__global__ __launch_bounds__(1024) void k_front_bin(
    const float* __restrict__ W1, const float* __restrict__ W2,
    unsigned short* __restrict__ w12s,
    const int* __restrict__ esrc, const int* __restrict__ edst,
    int* __restrict__ gcur, unsigned int* __restrict__ binned,
    int nEdges)
{
    __shared__ int hist[256];   // NB <= 256
    __shared__ int lcur[256];
    int bid = blockIdx.x;
    int t = threadIdx.x;
    if (bid < 8) {
        // W12 in B-frag order: chunk c=nt*4+ks; lane L; elem j:
        // k=ks*32+(L>>4)*8+j, n=nt*16+(L&15)
        int idx = bid * 1024 + t;                // 0..8191
        int c = idx >> 9, L = (idx >> 3) & 63, j = idx & 7;
        int nt = c >> 2, ks = c & 3;
        int k = ks * 32 + (L >> 4) * 8 + j;
        int n = nt * 16 + (L & 15);
        float s = 0.f;
        #pragma unroll 8
        for (int jj = 0; jj < HID_F; ++jj)
            s += W1[k * HID_F + jj] * W2[jj * OUT_F + n];
        w12s[idx] = f2bf(s);
    } else {
        int bb = bid - 8;                        // binning block 0..A-1
        if (t < 256) hist[t] = 0;
        __syncthreads();
        long long base = (long long)bb * EPB;
        #pragma unroll
        for (int k = 0; k < EPB / 1024; ++k) {
            long long e = base + k * 1024 + t;
            if (e < nEdges) atomicAdd(&hist[edst[e] >> BUCKET_SHIFT], 1);
        }
        __syncthreads();
        if (t < 256) {
            int h = hist[t];
            lcur[t] = (h > 0) ? atomicAdd(&gcur[t], h) : 0;
        }
        __syncthreads();
        #pragma unroll
        for (int k = 0; k < EPB / 1024; ++k) {
            long long e = base + k * 1024 + t;
            if (e < nEdges) {
                int s = esrc[e], d = edst[e];
                int b = d >> BUCKET_SHIFT;
                int pos = atomicAdd(&lcur[b], 1);
                binned[(size_t)b * CAP + pos] =
                    (((unsigned int)(d & (BUCKET_SZ - 1))) << 23) | (unsigned int)s;
            }
        }
    }
}

// ---- Per-bucket local CSR (512 threads, 1 thread/node) ------------------
__global__ __launch_bounds__(512) void k_localcsr(
    const unsigned int* __restrict__ binned, const int* __restrict__ gcur,
    int* __restrict__ rowbeg, int* __restrict__ rowend,
    int* __restrict__ eidx, int nNodes)
{
    __shared__ int ldeg[BUCKET_SZ];
    __shared__ int lscan[BUCKET_SZ];
    int t = threadIdx.x;          // 0..511
    ldeg[t] = 0;
    __syncthreads();
    int eb0 = blockIdx.x * CAP;
    int cnt = gcur[blockIdx.x];
    int node0 = blockIdx.x << BUCKET_SHIFT;
    for (int e = t; e < cnt; e += 512)
        atomicAdd(&ldeg[binned[eb0 + e] >> 23], 1);
    __syncthreads();
    int s = ldeg[t];
    lscan[t] = s;
    __syncthreads();
    for (int d = 1; d < 512; d <<= 1) {
        int add = (t >= d) ? lscan[t - d] : 0;
        __syncthreads();
        lscan[t] += add;
        __syncthreads();
    }
    int excl = lscan[t] - s;
    int n0 = node0 + t;
    if (n0 < nNodes) { rowbeg[n0] = eb0 + excl; rowend[n0] = eb0 + excl + s; }
    __syncthreads();
    ldeg[t] = excl;               // becomes local cursor
    __syncthreads();
    for (int e = t; e < cnt; e += 512) {
        unsigned int p = binned[eb0 + e];
        int dl = (int)(p >> 23), sv = (int)(p & 0x7fffffu);
        int pos = atomicAdd(&ldeg[dl], 1);
        eidx[eb0 + pos] = sv;
    }
}

// ---- y GEMM (MFMA): y[M,64] = x[M,128] @ W12, fp32 in, bf16 out ---------
// Reads x fp32 directly (no xconv stage), converts to bf16 in-register.
__global__ __launch_bounds__(256) void y_gemm(
    const float* __restrict__ x, const unsigned short* __restrict__ w12s,
    unsigned short* __restrict__ y, int nNodes)
{
    int wave = threadIdx.x >> 6, lane = threadIdx.x & 63;
    int m0 = blockIdx.x * 64 + wave * 16;
    if (m0 >= nNodes) return;
    int row = lane & 15, quad = lane >> 4;
    int rr = min(m0 + row, nNodes - 1);          // clamp tail reads in-bounds
    const float* aRow = x + (size_t)rr * IN_F + quad * 8;
    f32x4 acc[4] = {};
    const bf16x8* bBase = reinterpret_cast<const bf16x8*>(w12s) + lane;
    #pragma unroll
    for (int ks = 0; ks < 4; ++ks) {
        float4 a0 = *reinterpret_cast<const float4*>(aRow + ks * 32);
        float4 a1 = *reinterpret_cast<const float4*>(aRow + ks * 32 + 4);
        bf16x8 a;
        a[0] = (short)f2bf(a0.x); a[1] = (short)f2bf(a0.y);
        a[2] = (short)f2bf(a0.z); a[3] = (short)f2bf(a0.w);
        a[4] = (short)f2bf(a1.x); a[5] = (short)f2bf(a1.y);
        a[6] = (short)f2bf(a1.z); a[7] = (short)f2bf(a1.w);
        #pragma unroll
        for (int nt = 0; nt < 4; ++nt) {
            bf16x8 b = bBase[(nt * 4 + ks) * 64];
            acc[nt] = __builtin_amdgcn_mfma_f32_16x16x32_bf16(a, b, acc[nt], 0, 0, 0);
        }
    }
    size_t outBase = (size_t)(m0 + quad * 4) * OUT_F + row;
    #pragma unroll
    for (int i = 0; i < 4; ++i) {
        if (m0 + quad * 4 + i >= nNodes) break;   // tail guard
        #pragma unroll
        for (int nt = 0; nt < 4; ++nt)
            y[outBase + (size_t)i * OUT_F + nt * 16] = f2bf(acc[nt][i]);
    }
}

// ---- Layer-1 gather (64-dim): aggy[n] = y[n] + sum y[src], bf16 out -----
// Wide-gather: 8 lanes cover a 128B row (dwordx4/lane) -> 8 edges/instr.
__global__ __launch_bounds__(256) void gather1y(
    const unsigned short* __restrict__ y, const int* __restrict__ rowbeg,
    const int* __restrict__ rowend,
    const int* __restrict__ eidx, unsigned short* __restrict__ aggy, int nNodes)
{
    int n    = blockIdx.x * 4 + __builtin_amdgcn_readfirstlane(threadIdx.x >> 6);
    int lane = threadIdx.x & 63;
    if (n >= nNodes) return;
    int beg = __builtin_amdgcn_readfirstlane(rowbeg[n]);
    int end = __builtin_amdgcn_readfirstlane(rowend[n]);
    int g = lane >> 3;          // edge subgroup 0..7
    int f = lane & 7;           // 16B chunk within row
    float acc[8] = {0.f, 0.f, 0.f, 0.f, 0.f, 0.f, 0.f, 0.f};

    for (int e0 = beg; e0 < end; e0 += 64) {
        int cnt = min(64, end - e0);                 // uniform
        int e = (lane < cnt) ? eidx[e0 + lane] : 0;
        for (int i = 0; i < cnt; i += 32) {          // 32 edges per block
            uint4 v[4];
            unsigned int vmask[4];
            #pragma unroll
            for (int j = 0; j < 4; ++j) {
                int eij = i + 8 * j + g;
                int src = __builtin_amdgcn_ds_bpermute(eij << 2, e);
                int s0  = __builtin_amdgcn_readlane(e, i + 8 * j);
                bool valid = eij < cnt;
                vmask[j] = valid ? 0xffffffffu : 0u;
                src = valid ? src : s0;
                v[j] = *reinterpret_cast<const uint4*>(
                    y + (unsigned)src * OUT_F + (f << 3));
            }
            #pragma unroll
            for (int j = 0; j < 4; ++j) {
                unsigned int a0 = v[j].x & vmask[j], a1 = v[j].y & vmask[j];
                unsigned int a2 = v[j].z & vmask[j], a3 = v[j].w & vmask[j];
                acc[0] += bf2f_lo(a0); acc[1] += bf2f_hi(a0);
                acc[2] += bf2f_lo(a1); acc[3] += bf2f_hi(a1);
                acc[4] += bf2f_lo(a2); acc[5] += bf2f_hi(a2);
                acc[6] += bf2f_lo(a3); acc[7] += bf2f_hi(a3);
            }
        }
    }
    // cross-subgroup reduce (8 groups share feature chunks)
    #pragma unroll
    for (int k = 0; k < 8; ++k) {
        acc[k] += __shfl_xor(acc[k], 8);
        acc[k] += __shfl_xor(acc[k], 16);
        acc[k] += __shfl_xor(acc[k], 32);
    }
    // self row add
    uint4 sv = *reinterpret_cast<const uint4*>(y + (size_t)n * OUT_F + (f << 3));
    acc[0] += bf2f_lo(sv.x); acc[1] += bf2f_hi(sv.x);
    acc[2] += bf2f_lo(sv.y); acc[3] += bf2f_hi(sv.y);
    acc[4] += bf2f_lo(sv.z); acc[5] += bf2f_hi(sv.z);
    acc[6] += bf2f_lo(sv.w); acc[7] += bf2f_hi(sv.w);
    if (g == 0) {
        uint4 o;
        o.x = (unsigned int)f2bf(acc[0]) | ((unsigned int)f2bf(acc[1]) << 16);
        o.y = (unsigned int)f2bf(acc[2]) | ((unsigned int)f2bf(acc[3]) << 16);
        o.z = (unsigned int)f2bf(acc[4]) | ((unsigned int)f2bf(acc[5]) << 16);
        o.w = (unsigned int)f2bf(acc[6]) | ((unsigned int)f2bf(acc[7]) << 16);
        *reinterpret_cast<uint4*>(aggy + (size_t)n * OUT_F + (f << 3)) = o;
    }
}

// ---- Layer-2 gather: out[n] = aggy[n] + sum aggy[src], fp32 out ---------
__global__ __launch_bounds__(256) void gather2(
    const unsigned short* __restrict__ aggy, const int* __restrict__ rowbeg,
    const int* __restrict__ rowend,
    const int* __restrict__ eidx, float* __restrict__ out, int nNodes)
{
    int n    = blockIdx.x * 4 + __builtin_amdgcn_readfirstlane(threadIdx.x >> 6);
    int lane = threadIdx.x & 63;
    if (n >= nNodes) return;
    int beg = __builtin_amdgcn_readfirstlane(rowbeg[n]);
    int end = __builtin_amdgcn_readfirstlane(rowend[n]);
    int g = lane >> 3;          // edge subgroup 0..7
    int f = lane & 7;           // 16B chunk within row
    float acc[8] = {0.f, 0.f, 0.f, 0.f, 0.f, 0.f, 0.f, 0.f};

    for (int e0 = beg; e0 < end; e0 += 64) {
        int cnt = min(64, end - e0);                 // uniform
        int e = (lane < cnt) ? eidx[e0 + lane] : 0;
        for (int i = 0; i < cnt; i += 32) {          // 32 edges per block
            uint4 v[4];
            unsigned int vmask[4];
            #pragma unroll
            for (int j = 0; j < 4; ++j) {
                int eij = i + 8 * j + g;
                int src = __builtin_amdgcn_ds_bpermute(eij << 2, e);
                int s0  = __builtin_amdgcn_readlane(e, i + 8 * j);
                bool valid = eij < cnt;
                vmask[j] = valid ? 0xffffffffu : 0u;
                src = valid ? src : s0;
                v[j] = *reinterpret_cast<const uint4*>(
                    aggy + (unsigned)src * OUT_F + (f << 3));
            }
            #pragma unroll
            for (int j = 0; j < 4; ++j) {
                unsigned int a0 = v[j].x & vmask[j], a1 = v[j].y & vmask[j];
                unsigned int a2 = v[j].z & vmask[j], a3 = v[j].w & vmask[j];
                acc[0] += bf2f_lo(a0); acc[1] += bf2f_hi(a0);
                acc[2] += bf2f_lo(a1); acc[3] += bf2f_hi(a1);
                acc[4] += bf2f_lo(a2); acc[5] += bf2f_hi(a2);
                acc[6] += bf2f_lo(a3); acc[7] += bf2f_hi(a3);
            }
        }
    }
    // cross-subgroup reduce (8 groups share feature chunks)
    #pragma unroll
    for (int k = 0; k < 8; ++k) {
        acc[k] += __shfl_xor(acc[k], 8);
        acc[k] += __shfl_xor(acc[k], 16);
        acc[k] += __shfl_xor(acc[k], 32);
    }
    // self row add
    uint4 sv = *reinterpret_cast<const uint4*>(aggy + (size_t)n * OUT_F + (f << 3));
    acc[0] += bf2f_lo(sv.x); acc[1] += bf2f_hi(sv.x);
    acc[2] += bf2f_lo(sv.y); acc[3] += bf2f_hi(sv.y);
    acc[4] += bf2f_lo(sv.z); acc[5] += bf2f_hi(sv.z);
    acc[6] += bf2f_lo(sv.w); acc[7] += bf2f_hi(sv.w);
    if (g == 0) {
        float* o = out + (size_t)n * OUT_F + (f << 3);
        *reinterpret_cast<float4*>(o)     = make_float4(acc[0], acc[1], acc[2], acc[3]);
        *reinterpret_cast<float4*>(o + 4) = make_float4(acc[4], acc[5], acc[6], acc[7]);
    }
}

extern "C" void kernel_launch(void* const* d_in, const int* in_sizes, int n_in,
                              void* d_out, int out_size, void* d_ws, size_t ws_size,
                              hipStream_t stream) {
    const float* x  = (const float*)d_in[0];
    const int* esrc = (const int*)d_in[1];
    const int* edst = (const int*)d_in[2];
    const float* W1 = (const float*)d_in[3];
    const float* W2 = (const float*)d_in[4];
    float* out      = (float*)d_out;

    const int nNodes = in_sizes[0] / IN_F;
    const int nEdges = in_sizes[1];
    const int NB = (nNodes + BUCKET_SZ - 1) / BUCKET_SZ;   // 196 (<= 256)
    const int A  = (nEdges + EPB - 1) / EPB;               // 391 binning blocks

    // Workspace (~42 MB; 110.4 MB known-safe), 64B-aligned segments.
    char* ws = (char*)d_ws;
    size_t off = 0;
    auto alloc = [&](size_t bytes) {
        char* p = ws + off; off = (off + bytes + 63) & ~(size_t)63; return p;
    };
    unsigned short* y    = (unsigned short*)alloc((size_t)nNodes * OUT_F * 2);
    unsigned short* aggy = (unsigned short*)alloc((size_t)nNodes * OUT_F * 2);
    unsigned int* binned = (unsigned int*)alloc((size_t)NB * CAP * 4);
    int* eidx            = (int*)alloc((size_t)NB * CAP * 4);
    unsigned short* w12s = (unsigned short*)alloc((size_t)IN_F * OUT_F * 2);
    int* rowbeg          = (int*)alloc((size_t)nNodes * 4);
    int* rowend          = (int*)alloc((size_t)nNodes * 4);
    int* gcur            = (int*)alloc(256 * 4);

    hipMemsetAsync(gcur, 0, 256 * 4, stream);

    // ---- fused front: W12 | bin ----
    k_front_bin<<<8 + A, 1024, 0, stream>>>(
        W1, W2, w12s, esrc, edst, gcur, binned, nEdges);

    k_localcsr<<<NB, 512, 0, stream>>>(binned, gcur, rowbeg, rowend, eidx, nNodes);

    const int mBlocks = (nNodes + 63) / 64;
    const int nBlocks = (nNodes + 3) / 4;
    y_gemm<<<mBlocks, 256, 0, stream>>>(x, w12s, y, nNodes);
    gather1y<<<nBlocks, 256, 0, stream>>>(y, rowbeg, rowend, eidx, aggy, nNodes);
    gather2<<<nBlocks, 256, 0, stream>>>(aggy, rowbeg, rowend, eidx, out, nNodes);
}